// Round 2
// baseline (581.772 us; speedup 1.0000x reference)
//
#include <hip/hip_runtime.h>

#define NS 128                 // samples per ray
#define RPB 4                  // rays per block (4 waves of 64)
#define NEAR_P 2.0f
#define FAR_P  6.0f

// One wave (64 lanes) per ray; each lane handles samples z0=2*lane, z1=2*lane+1.
// Radiance is staged through LDS with perfectly coalesced float4 loads:
// the block's 4 rays are contiguous in memory (radiances is [nrays][128][3]),
// so the 6 KiB block span = 384 float4s loaded by 256 threads.
__global__ __launch_bounds__(256) void volrender_kernel(
    const float* __restrict__ sigmas,      // [nrays, 128]
    const float* __restrict__ radiances,   // [nrays, 128, 3]
    float* __restrict__ out_rgb,           // [nrays, 3]
    float* __restrict__ out_depth,         // [nrays]
    int nrays)
{
    __shared__ float s_rad[RPB * NS * 3];  // 6 KiB

    const int tid  = threadIdx.x;
    const int lane = tid & 63;
    const int wave = tid >> 6;
    const int ray0 = blockIdx.x * RPB;
    const int ray  = ray0 + wave;

    // ---- stage radiance for the block's 4 rays (coalesced float4) ----
    {
        const float4* gsrc = (const float4*)(radiances + (size_t)ray0 * NS * 3);
        float4* ldst = (float4*)s_rad;
        // 384 float4s, 256 threads: threads 0..127 do 2, rest do 1
        ldst[tid] = gsrc[tid];
        if (tid < RPB * NS * 3 / 4 - 256)
            ldst[tid + 256] = gsrc[tid + 256];
    }

    // ---- sigma: direct global float2, already perfectly coalesced ----
    const float2 s2 = *(const float2*)(sigmas + (size_t)ray * NS + 2 * lane);

    __syncthreads();

    const float dz = (FAR_P - NEAR_P) / (float)(NS - 1);

    const float* rad = s_rad + wave * NS * 3;
    const float2 rA = *(const float2*)(rad + 6 * lane);       // r(z0), g(z0)
    const float2 rB = *(const float2*)(rad + 6 * lane + 2);   // b(z0), r(z1)
    const float2 rC = *(const float2*)(rad + 6 * lane + 4);   // g(z1), b(z1)

    const int z0 = 2 * lane;
    const int z1 = z0 + 1;
    const float d1 = (z1 == NS - 1) ? 1e10f : dz;

    // alpha = 1 - exp(-sigma*dist)
    const float a0 = 1.0f - __expf(-s2.x * dz);
    const float a1 = 1.0f - __expf(-s2.y * d1);

    // transmittance step factors: 1 - alpha + 1e-10
    const float t0 = 1.0f - a0 + 1e-10f;
    const float t1 = 1.0f - a1 + 1e-10f;

    // inclusive prefix product across the wave (Kogge-Stone on 2-sample products)
    float incl = t0 * t1;
    #pragma unroll
    for (int off = 1; off < 64; off <<= 1) {
        float v = __shfl_up(incl, off, 64);
        if (lane >= off) incl *= v;
    }
    float excl = __shfl_up(incl, 1, 64);
    if (lane == 0) excl = 1.0f;

    const float Ts0 = excl * t0;
    const float Ts1 = Ts0 * t1;

    const float w0 = a0 * Ts0;
    const float w1 = a1 * Ts1;

    const float zv0 = NEAR_P + (float)z0 * dz;
    const float zv1 = NEAR_P + (float)z1 * dz;

    float pr = w0 * rA.x + w1 * rB.y;
    float pg = w0 * rA.y + w1 * rC.x;
    float pb = w0 * rB.x + w1 * rC.y;
    float pd = w0 * zv0  + w1 * zv1;

    // wave tree-reduction
    #pragma unroll
    for (int off = 32; off > 0; off >>= 1) {
        pr += __shfl_down(pr, off, 64);
        pg += __shfl_down(pg, off, 64);
        pb += __shfl_down(pb, off, 64);
        pd += __shfl_down(pd, off, 64);
    }

    if (lane == 0 && ray < nrays) {
        float* o = out_rgb + (size_t)ray * 3;
        o[0] = pr;
        o[1] = pg;
        o[2] = pb;
        out_depth[ray] = pd;
    }
}

extern "C" void kernel_launch(void* const* d_in, const int* in_sizes, int n_in,
                              void* d_out, int out_size, void* d_ws, size_t ws_size,
                              hipStream_t stream) {
    const float* sigmas    = (const float*)d_in[0];
    const float* radiances = (const float*)d_in[1];
    float* out = (float*)d_out;

    const int nrays = in_sizes[0] / NS;        // B * NUM_RAYS = 262144
    float* out_rgb   = out;                    // [nrays, 3]
    float* out_depth = out + (size_t)nrays * 3;

    const int grid = (nrays + RPB - 1) / RPB;
    volrender_kernel<<<grid, 256, 0, stream>>>(sigmas, radiances, out_rgb, out_depth, nrays);
}